// Round 1
// baseline (164.766 us; speedup 1.0000x reference)
//
#include <hip/hip_runtime.h>
#include <stdint.h>

#define NTOK 256
#define NOUT 128
#define DIM 64
#define NB 128
#define CAP 2048
#define NTILES 2080   // 4x4 tiles over upper triangle incl. diagonal blocks: sum_{k=1..64} k
#define NMERGE 128
#define KAPPA 0.21f

// LDS layout (bytes):
//   knT    [64][256] f32 : 65536  @ 0
//   keys   [2048] u64    : 16384  @ 65536
//   accO   [128][64] f32 : 32768  @ 81920
//   gid    [256] i32     : 1024   @ 114688
//   cnt256 [256] i32     : 1024   @ 115712
//   scn    [256] i32     : 1024   @ 116736
//   rep    [128] i32     : 512    @ 117760
//   red    [8]  u64      : 64     @ 118272
//   bkey   u64           : 8      @ 118336
//   misc   [4]  i32      : 16     @ 118344  ([0]=cnt,[1]=cntClamped,[2]=overflowMode,[3]=mergesDoneByWalk)
#define SMEM_BYTES 118400

__device__ __forceinline__ unsigned mono_f32(float s) {
  unsigned u = __float_as_uint(s);
  return (u & 0x80000000u) ? ~u : (u | 0x80000000u);
}

__global__ __launch_bounds__(512) void gm_kernel(const float* __restrict__ K,
                                                 const float* __restrict__ V,
                                                 float* __restrict__ OUT) {
  extern __shared__ char smem[];
  float* knT = (float*)smem;
  unsigned long long* keys = (unsigned long long*)(smem + 65536);
  float* accO = (float*)(smem + 81920);
  int* gid = (int*)(smem + 114688);
  int* cnt256 = (int*)(smem + 115712);
  int* scn = (int*)(smem + 116736);
  int* rep = (int*)(smem + 117760);
  unsigned long long* red = (unsigned long long*)(smem + 118272);
  unsigned long long* bkey = (unsigned long long*)(smem + 118336);
  int* misc = (int*)(smem + 118344);

  const int tid = threadIdx.x;
  const int lane = tid & 63;
  const int wid = tid >> 6;
  const int b = blockIdx.x;

  // ---- init ----
  for (int e = tid; e < CAP; e += 512) keys[e] = 0ULL;
  if (tid < 256) gid[tid] = tid;
  if (tid == 0) misc[0] = 0;

  // ---- phase 1: load k rows, normalize, store transposed knT[d][t] ----
  {
    const int t = tid >> 1, h = tid & 1;
    const float* kp = K + ((size_t)b * NTOK + t) * DIM + h * 32;
    double ss = 0.0;
    float vals[32];
#pragma unroll
    for (int q = 0; q < 8; ++q) {
      float4 v4 = *reinterpret_cast<const float4*>(kp + q * 4);
      vals[q * 4 + 0] = v4.x; vals[q * 4 + 1] = v4.y;
      vals[q * 4 + 2] = v4.z; vals[q * 4 + 3] = v4.w;
      ss += (double)v4.x * v4.x + (double)v4.y * v4.y +
            (double)v4.z * v4.z + (double)v4.w * v4.w;
    }
    double other = __shfl_xor(ss, 1);
    double nrm = sqrt(ss + other);
#pragma unroll
    for (int q = 0; q < 32; ++q)
      knT[(h * 32 + q) * NTOK + t] = (float)((double)vals[q] / nrm);
  }
  __syncthreads();

  // ---- phase 2: gram tiles (4x4, f64 accumulate) + threshold collect ----
  for (int T = tid; T < NTILES; T += 512) {
    float tf = (129.0f - sqrtf(129.0f * 129.0f - 8.0f * (float)T)) * 0.5f;
    int ti = (int)tf;
    if (ti < 0) ti = 0;
    if (ti > 63) ti = 63;
    while (ti < 63 && (ti + 1) * (129 - (ti + 1)) / 2 <= T) ++ti;
    while (ti > 0 && ti * (129 - ti) / 2 > T) --ti;
    int tj = ti + (T - ti * (129 - ti) / 2);
    int i0 = ti * 4, j0 = tj * 4;

    double acc[4][4] = {};
#pragma unroll 4
    for (int d = 0; d < 64; ++d) {
      const float4 av = *reinterpret_cast<const float4*>(knT + d * NTOK + i0);
      const float4 bv = *reinterpret_cast<const float4*>(knT + d * NTOK + j0);
      double aa[4] = {(double)av.x, (double)av.y, (double)av.z, (double)av.w};
      double bb[4] = {(double)bv.x, (double)bv.y, (double)bv.z, (double)bv.w};
#pragma unroll
      for (int r = 0; r < 4; ++r)
#pragma unroll
        for (int c = 0; c < 4; ++c)
          acc[r][c] = fma(aa[r], bb[c], acc[r][c]);
    }
#pragma unroll
    for (int r = 0; r < 4; ++r)
#pragma unroll
      for (int c = 0; c < 4; ++c) {
        int i = i0 + r, j = j0 + c;
        if (i < j) {
          float s = (float)acc[r][c];
          if (s >= KAPPA) {
            unsigned u = mono_f32(s);
            unsigned long long key =
                ((unsigned long long)u << 16) |
                (unsigned)(65535 - ((i << 8) | j));
            int idx = atomicAdd(&misc[0], 1);
            if (idx < CAP) keys[idx] = key;
          }
        }
      }
  }
  __syncthreads();
  if (tid == 0) {
    int c = misc[0];
    misc[1] = c > CAP ? CAP : c;
    misc[2] = c > CAP ? 1 : 0;          // overflow -> fallback everything
    misc[3] = c > CAP ? 0 : NMERGE;     // walk overwrites when it runs
  }
  __syncthreads();

  // ---- phase 3: bitonic sort (descending) of 2048 keys ----
  for (int kk = 2; kk <= CAP; kk <<= 1) {
    for (int jj = kk >> 1; jj > 0; jj >>= 1) {
      __syncthreads();
      for (int e = tid; e < CAP; e += 512) {
        int p = e ^ jj;
        if (p > e) {
          unsigned long long a = keys[e], c = keys[p];
          bool up = ((e & kk) == 0);
          bool sw = up ? (a < c) : (a > c);
          if (sw) { keys[e] = c; keys[p] = a; }
        }
      }
    }
  }
  __syncthreads();

  // ---- phase 4: single-wave Kruskal walk over sorted list ----
  if (misc[2] == 0 && tid < 64) {
    const int cntC = misc[1];
    int cursor = 0;
    int done = 0;
    for (int mg = 0; mg < NMERGE; ++mg) {
      int f = -1, pi = 0, pj = 0;
      for (;;) {
        int idx = cursor + lane;
        unsigned long long key = (idx < cntC) ? keys[idx] : 0ULL;
        pi = 255 - (int)((key >> 8) & 255);
        pj = 255 - (int)(key & 255);
        bool valid = (key != 0ULL) && (gid[pi] != gid[pj]);
        unsigned long long mask = __ballot(valid);
        if (mask) {
          f = __ffsll((long long)mask) - 1;
          cursor += f + 1;
          break;
        }
        cursor += 64;
        if (cursor >= cntC) break;
      }
      if (f < 0) break;  // exhausted -> fallback resumes at 'done'
      int spi = __shfl(pi, f), spj = __shfl(pj, f);
      int gi = gid[spi], gj = gid[spj];
#pragma unroll
      for (int r = 0; r < 4; ++r) {
        int t = r * 64 + lane;
        if (gid[t] == gi) gid[t] = gj;
      }
      __threadfence_block();  // wave-internal LDS ordering for next scan
      done = mg + 1;
    }
    if (lane == 0) misc[3] = done;
  }
  __syncthreads();

  // ---- phase 5: fallback (exact, rarely/never taken): full argmax per merge ----
  {
    const int start = misc[3];
    for (int mg = start; mg < NMERGE; ++mg) {
      unsigned long long best = 0ULL;
      const int p = tid >> 2, q = tid & 3;
      const int jA = 128 + p, jB = 127 - p;
      const int lenA = jA;
      int e0 = q * 64, e1 = (q == 3) ? 255 : (q * 64 + 64);
      for (int e = e0; e < e1; ++e) {
        int i = (e < lenA) ? e : (e - lenA);
        int j = (e < lenA) ? jA : jB;
        if (gid[i] != gid[j]) {
          double s = 0.0;
          for (int d = 0; d < 64; ++d)
            s = fma((double)knT[d * NTOK + i], (double)knT[d * NTOK + j], s);
          unsigned u = mono_f32((float)s);
          unsigned long long key =
              ((unsigned long long)u << 16) |
              (unsigned)(65535 - ((i << 8) | j));
          if (key > best) best = key;
        }
      }
#pragma unroll
      for (int off = 32; off; off >>= 1) {
        unsigned long long o = __shfl_down(best, off);
        if (o > best) best = o;
      }
      if (lane == 0) red[wid] = best;
      __syncthreads();
      if (tid == 0) {
        unsigned long long mx = 0ULL;
        for (int w = 0; w < 8; ++w)
          if (red[w] > mx) mx = red[w];
        bkey[0] = mx;
      }
      __syncthreads();
      unsigned long long bk = bkey[0];
      int pi = 255 - (int)((bk >> 8) & 255);
      int pj = 255 - (int)(bk & 255);
      int gi = gid[pi], gj = gid[pj];
      __syncthreads();
      if (tid < 256 && gid[tid] == gi) gid[tid] = gj;
      __syncthreads();
    }
  }
  __syncthreads();

  // ---- phase 6: sizes, slots (alive reps ascending), accumulate means ----
  if (tid < 256) cnt256[tid] = 0;
  __syncthreads();
  if (tid < 256) atomicAdd(&cnt256[gid[tid]], 1);
  __syncthreads();
  if (tid < 256) scn[tid] = (cnt256[tid] != 0) ? 1 : 0;
  __syncthreads();
  for (int off = 1; off < 256; off <<= 1) {
    int add = 0;
    if (tid < 256 && tid >= off) add = scn[tid - off];
    __syncthreads();
    if (tid < 256) scn[tid] += add;
    __syncthreads();
  }
  if (tid < 256 && cnt256[tid]) rep[scn[tid] - 1] = tid;
  __syncthreads();
  for (int e = tid; e < NOUT * DIM; e += 512) accO[e] = 0.0f;
  __syncthreads();
  {
    const int t = tid >> 1, h = tid & 1;
    const int slot = scn[gid[t]] - 1;
    const float* vp = V + ((size_t)b * NTOK + t) * DIM + h * 32;
    float* dst = accO + slot * DIM + h * 32;
#pragma unroll
    for (int q = 0; q < 8; ++q) {
      float4 v4 = *reinterpret_cast<const float4*>(vp + q * 4);
      atomicAdd(&dst[q * 4 + 0], v4.x);
      atomicAdd(&dst[q * 4 + 1], v4.y);
      atomicAdd(&dst[q * 4 + 2], v4.z);
      atomicAdd(&dst[q * 4 + 3], v4.w);
    }
  }
  __syncthreads();

  // ---- phase 7: write outputs ----
  float* outMain = OUT + (size_t)b * (NOUT * DIM);
  for (int e = tid; e < NOUT * DIM; e += 512) {
    int o = e >> 6;
    float sz = (float)cnt256[rep[o]];
    outMain[e] = accO[e] / sz;
  }
  float* outSz = OUT + (size_t)NB * NOUT * DIM + (size_t)b * NOUT;
  for (int o = tid; o < NOUT; o += 512) outSz[o] = (float)cnt256[rep[o]];
}

extern "C" void kernel_launch(void* const* d_in, const int* in_sizes, int n_in,
                              void* d_out, int out_size, void* d_ws, size_t ws_size,
                              hipStream_t stream) {
  const float* K = (const float*)d_in[0];
  const float* V = (const float*)d_in[1];
  float* OUT = (float*)d_out;
  (void)in_sizes; (void)n_in; (void)out_size; (void)d_ws; (void)ws_size;
  hipFuncSetAttribute(reinterpret_cast<const void*>(gm_kernel),
                      hipFuncAttributeMaxDynamicSharedMemorySize, SMEM_BYTES);
  gm_kernel<<<dim3(NB), dim3(512), SMEM_BYTES, stream>>>(K, V, OUT);
}

// Round 2
// 128.528 us; speedup vs baseline: 1.2820x; 1.2820x over previous
//
#include <hip/hip_runtime.h>
#include <stdint.h>

#define NTOK 256
#define NOUT 128
#define DIM 64
#define NB 128
#define CAP 2048
#define NTILES 2080   // 4x4 tiles over upper triangle incl. diagonal blocks: sum_{k=1..64} k
#define NMERGE 128
#define KAPPA 0.21f

// LDS layout (bytes):
//   knT    [64][256] f32 : 65536  @ 0
//   keys   [2048] u64    : 16384  @ 65536
//   accO   [128][64] f32 : 32768  @ 81920
//   gid    [256] i32     : 1024   @ 114688
//   cnt256 [256] i32     : 1024   @ 115712
//   scn    [256] i32     : 1024   @ 116736
//   rep    [128] i32     : 512    @ 117760
//   red    [8]  u64      : 64     @ 118272
//   bkey   u64           : 8      @ 118336
//   misc   [4]  i32      : 16     @ 118344  ([0]=cnt,[1]=cntClamped,[2]=overflowMode,[3]=mergesDoneByWalk)
#define SMEM_BYTES 118400

__device__ __forceinline__ unsigned mono_f32(float s) {
  unsigned u = __float_as_uint(s);
  return (u & 0x80000000u) ? ~u : (u | 0x80000000u);
}

__device__ __forceinline__ unsigned long long shflx64(unsigned long long x, int m) {
  unsigned lo = (unsigned)x, hi = (unsigned)(x >> 32);
  lo = __shfl_xor(lo, m);
  hi = __shfl_xor(hi, m);
  return ((unsigned long long)hi << 32) | lo;
}

#define CEX(a, b, up)                         \
  do {                                        \
    unsigned long long _a = (a), _b = (b);    \
    bool _sw = (up) ? (_a < _b) : (_a > _b);  \
    if (_sw) { (a) = _b; (b) = _a; }          \
  } while (0)

#define KEEP(v, o, km) ((km) ? ((v) > (o) ? (v) : (o)) : ((v) < (o) ? (v) : (o)))

__global__ __launch_bounds__(512) void gm_kernel(const float* __restrict__ K,
                                                 const float* __restrict__ V,
                                                 float* __restrict__ OUT) {
  extern __shared__ char smem[];
  float* knT = (float*)smem;
  unsigned long long* keys = (unsigned long long*)(smem + 65536);
  float* accO = (float*)(smem + 81920);
  int* gid = (int*)(smem + 114688);
  int* cnt256 = (int*)(smem + 115712);
  int* scn = (int*)(smem + 116736);
  int* rep = (int*)(smem + 117760);
  unsigned long long* red = (unsigned long long*)(smem + 118272);
  unsigned long long* bkey = (unsigned long long*)(smem + 118336);
  int* misc = (int*)(smem + 118344);

  const int tid = threadIdx.x;
  const int lane = tid & 63;
  const int wid = tid >> 6;
  const int b = blockIdx.x;

  // ---- init ----
  for (int e = tid; e < CAP; e += 512) keys[e] = 0ULL;
  if (tid < 256) gid[tid] = tid;
  if (tid == 0) misc[0] = 0;

  // ---- phase 1: load k rows, normalize, store transposed knT[d][t] ----
  {
    const int t = tid >> 1, h = tid & 1;
    const float* kp = K + ((size_t)b * NTOK + t) * DIM + h * 32;
    double ss = 0.0;
    float vals[32];
#pragma unroll
    for (int q = 0; q < 8; ++q) {
      float4 v4 = *reinterpret_cast<const float4*>(kp + q * 4);
      vals[q * 4 + 0] = v4.x; vals[q * 4 + 1] = v4.y;
      vals[q * 4 + 2] = v4.z; vals[q * 4 + 3] = v4.w;
      ss += (double)v4.x * v4.x + (double)v4.y * v4.y +
            (double)v4.z * v4.z + (double)v4.w * v4.w;
    }
    double other = __shfl_xor(ss, 1);
    double nrm = sqrt(ss + other);
#pragma unroll
    for (int q = 0; q < 32; ++q)
      knT[(h * 32 + q) * NTOK + t] = (float)((double)vals[q] / nrm);
  }
  __syncthreads();

  // ---- phase 2: gram tiles (4x4, f64 accumulate) + threshold collect ----
  for (int T = tid; T < NTILES; T += 512) {
    float tf = (129.0f - sqrtf(129.0f * 129.0f - 8.0f * (float)T)) * 0.5f;
    int ti = (int)tf;
    if (ti < 0) ti = 0;
    if (ti > 63) ti = 63;
    while (ti < 63 && (ti + 1) * (129 - (ti + 1)) / 2 <= T) ++ti;
    while (ti > 0 && ti * (129 - ti) / 2 > T) --ti;
    int tj = ti + (T - ti * (129 - ti) / 2);
    int i0 = ti * 4, j0 = tj * 4;

    double acc[4][4] = {};
#pragma unroll 4
    for (int d = 0; d < 64; ++d) {
      const float4 av = *reinterpret_cast<const float4*>(knT + d * NTOK + i0);
      const float4 bv = *reinterpret_cast<const float4*>(knT + d * NTOK + j0);
      double aa[4] = {(double)av.x, (double)av.y, (double)av.z, (double)av.w};
      double bb[4] = {(double)bv.x, (double)bv.y, (double)bv.z, (double)bv.w};
#pragma unroll
      for (int r = 0; r < 4; ++r)
#pragma unroll
        for (int c = 0; c < 4; ++c)
          acc[r][c] = fma(aa[r], bb[c], acc[r][c]);
    }
#pragma unroll
    for (int r = 0; r < 4; ++r)
#pragma unroll
      for (int c = 0; c < 4; ++c) {
        int i = i0 + r, j = j0 + c;
        if (i < j) {
          float s = (float)acc[r][c];
          if (s >= KAPPA) {
            unsigned u = mono_f32(s);
            unsigned long long key =
                ((unsigned long long)u << 16) |
                (unsigned)(65535 - ((i << 8) | j));
            int idx = atomicAdd(&misc[0], 1);
            if (idx < CAP) keys[idx] = key;
          }
        }
      }
  }
  __syncthreads();
  if (tid == 0) {
    int c = misc[0];
    misc[1] = c > CAP ? CAP : c;
    misc[2] = c > CAP ? 1 : 0;          // overflow -> fallback everything
    misc[3] = c > CAP ? 0 : NMERGE;     // walk overwrites when it runs
  }
  __syncthreads();

  // ---- phase 3: register-resident bitonic sort (descending) of 2048 keys ----
  // Thread owns 4 consecutive elements e0..e0+3. jj>=256: LDS; 4<=jj<=128:
  // shfl_xor within wave; jj<=2: thread-local. Only 6 of 66 stages hit LDS.
  {
    const int e0 = 4 * tid;
    unsigned long long v0 = keys[e0], v1 = keys[e0 + 1],
                       v2 = keys[e0 + 2], v3 = keys[e0 + 3];
    for (int kk = 2; kk <= CAP; kk <<= 1) {
      for (int jj = kk >> 1; jj > 0; jj >>= 1) {
        if (jj >= 256) {
          __syncthreads();
          keys[e0] = v0; keys[e0 + 1] = v1; keys[e0 + 2] = v2; keys[e0 + 3] = v3;
          __syncthreads();
          const int p0 = e0 ^ jj;
          unsigned long long o0 = keys[p0], o1 = keys[p0 + 1],
                             o2 = keys[p0 + 2], o3 = keys[p0 + 3];
          const bool km = ((e0 & kk) == 0) == ((e0 & jj) == 0);
          v0 = KEEP(v0, o0, km); v1 = KEEP(v1, o1, km);
          v2 = KEEP(v2, o2, km); v3 = KEEP(v3, o3, km);
        } else if (jj >= 4) {
          const int m = jj >> 2;
          unsigned long long o0 = shflx64(v0, m), o1 = shflx64(v1, m),
                             o2 = shflx64(v2, m), o3 = shflx64(v3, m);
          const bool km = ((e0 & kk) == 0) == ((e0 & jj) == 0);
          v0 = KEEP(v0, o0, km); v1 = KEEP(v1, o1, km);
          v2 = KEEP(v2, o2, km); v3 = KEEP(v3, o3, km);
        } else if (jj == 2) {
          const bool up = ((e0 & kk) == 0);
          CEX(v0, v2, up); CEX(v1, v3, up);
        } else {  // jj == 1
          bool up0, up1;
          if (kk == 2) { up0 = true; up1 = false; }
          else { up0 = up1 = ((e0 & kk) == 0); }
          CEX(v0, v1, up0); CEX(v2, v3, up1);
        }
      }
    }
    __syncthreads();
    keys[e0] = v0; keys[e0 + 1] = v1; keys[e0 + 2] = v2; keys[e0 + 3] = v3;
  }
  __syncthreads();

  // ---- phase 4: single-wave Kruskal walk, gid in registers ----
  // Token t's group id lives in wave 0: lane (t&63), reg (t>>6).
  if (misc[2] == 0 && wid == 0) {
    const int cntC = misc[1];
    int rg0 = lane, rg1 = 64 + lane, rg2 = 128 + lane, rg3 = 192 + lane;
    int cursor = 0, done = 0;
    for (int mg = 0; mg < NMERGE; ++mg) {
      int f = -1, gpi = 0, gpj = 0;
      for (;;) {
        const int idx = cursor + lane;
        const unsigned long long key = (idx < cntC) ? keys[idx] : 0ULL;
        const int pi = 255 - (int)((key >> 8) & 255);
        const int pj = 255 - (int)(key & 255);
        const int sli = pi & 63, ssi = pi >> 6;
        const int slj = pj & 63, ssj = pj >> 6;
        const int a0 = __shfl(rg0, sli), a1 = __shfl(rg1, sli),
                  a2 = __shfl(rg2, sli), a3 = __shfl(rg3, sli);
        const int b0 = __shfl(rg0, slj), b1 = __shfl(rg1, slj),
                  b2 = __shfl(rg2, slj), b3 = __shfl(rg3, slj);
        gpi = (ssi == 0) ? a0 : (ssi == 1) ? a1 : (ssi == 2) ? a2 : a3;
        gpj = (ssj == 0) ? b0 : (ssj == 1) ? b1 : (ssj == 2) ? b2 : b3;
        const bool valid = (key != 0ULL) && (gpi != gpj);
        const unsigned long long mask = __ballot(valid);
        if (mask) {
          f = __ffsll((long long)mask) - 1;
          cursor += f + 1;
          break;
        }
        cursor += 64;
        if (cursor >= cntC) break;
      }
      if (f < 0) break;  // exhausted -> fallback resumes at 'done'
      const int gi = __shfl(gpi, f), gj = __shfl(gpj, f);
      if (rg0 == gi) rg0 = gj;
      if (rg1 == gi) rg1 = gj;
      if (rg2 == gi) rg2 = gj;
      if (rg3 == gi) rg3 = gj;
      done = mg + 1;
    }
    gid[lane] = rg0; gid[64 + lane] = rg1;
    gid[128 + lane] = rg2; gid[192 + lane] = rg3;
    if (lane == 0) misc[3] = done;
  }
  __syncthreads();

  // ---- phase 5: fallback (exact, rarely/never taken): full argmax per merge ----
  {
    const int start = misc[3];
    for (int mg = start; mg < NMERGE; ++mg) {
      unsigned long long best = 0ULL;
      const int p = tid >> 2, q = tid & 3;
      const int jA = 128 + p, jB = 127 - p;
      const int lenA = jA;
      int e0 = q * 64, e1 = (q == 3) ? 255 : (q * 64 + 64);
      for (int e = e0; e < e1; ++e) {
        int i = (e < lenA) ? e : (e - lenA);
        int j = (e < lenA) ? jA : jB;
        if (gid[i] != gid[j]) {
          double s = 0.0;
          for (int d = 0; d < 64; ++d)
            s = fma((double)knT[d * NTOK + i], (double)knT[d * NTOK + j], s);
          unsigned u = mono_f32((float)s);
          unsigned long long key =
              ((unsigned long long)u << 16) |
              (unsigned)(65535 - ((i << 8) | j));
          if (key > best) best = key;
        }
      }
#pragma unroll
      for (int off = 32; off; off >>= 1) {
        unsigned long long o = __shfl_down(best, off);
        if (o > best) best = o;
      }
      if (lane == 0) red[wid] = best;
      __syncthreads();
      if (tid == 0) {
        unsigned long long mx = 0ULL;
        for (int w = 0; w < 8; ++w)
          if (red[w] > mx) mx = red[w];
        bkey[0] = mx;
      }
      __syncthreads();
      unsigned long long bk = bkey[0];
      int pi = 255 - (int)((bk >> 8) & 255);
      int pj = 255 - (int)(bk & 255);
      int gi = gid[pi], gj = gid[pj];
      __syncthreads();
      if (tid < 256 && gid[tid] == gi) gid[tid] = gj;
      __syncthreads();
    }
  }
  __syncthreads();

  // ---- phase 6: sizes, slots (alive reps ascending), accumulate means ----
  if (tid < 256) cnt256[tid] = 0;
  __syncthreads();
  if (tid < 256) atomicAdd(&cnt256[gid[tid]], 1);
  __syncthreads();
  if (tid < 256) scn[tid] = (cnt256[tid] != 0) ? 1 : 0;
  __syncthreads();
  for (int off = 1; off < 256; off <<= 1) {
    int add = 0;
    if (tid < 256 && tid >= off) add = scn[tid - off];
    __syncthreads();
    if (tid < 256) scn[tid] += add;
    __syncthreads();
  }
  if (tid < 256 && cnt256[tid]) rep[scn[tid] - 1] = tid;
  __syncthreads();
  for (int e = tid; e < NOUT * DIM; e += 512) accO[e] = 0.0f;
  __syncthreads();
  {
    const int t = tid >> 1, h = tid & 1;
    const int slot = scn[gid[t]] - 1;
    const float* vp = V + ((size_t)b * NTOK + t) * DIM + h * 32;
    float* dst = accO + slot * DIM + h * 32;
#pragma unroll
    for (int q = 0; q < 8; ++q) {
      float4 v4 = *reinterpret_cast<const float4*>(vp + q * 4);
      atomicAdd(&dst[q * 4 + 0], v4.x);
      atomicAdd(&dst[q * 4 + 1], v4.y);
      atomicAdd(&dst[q * 4 + 2], v4.z);
      atomicAdd(&dst[q * 4 + 3], v4.w);
    }
  }
  __syncthreads();

  // ---- phase 7: write outputs ----
  float* outMain = OUT + (size_t)b * (NOUT * DIM);
  for (int e = tid; e < NOUT * DIM; e += 512) {
    int o = e >> 6;
    float sz = (float)cnt256[rep[o]];
    outMain[e] = accO[e] / sz;
  }
  float* outSz = OUT + (size_t)NB * NOUT * DIM + (size_t)b * NOUT;
  for (int o = tid; o < NOUT; o += 512) outSz[o] = (float)cnt256[rep[o]];
}

extern "C" void kernel_launch(void* const* d_in, const int* in_sizes, int n_in,
                              void* d_out, int out_size, void* d_ws, size_t ws_size,
                              hipStream_t stream) {
  const float* K = (const float*)d_in[0];
  const float* V = (const float*)d_in[1];
  float* OUT = (float*)d_out;
  (void)in_sizes; (void)n_in; (void)out_size; (void)d_ws; (void)ws_size;
  hipFuncSetAttribute(reinterpret_cast<const void*>(gm_kernel),
                      hipFuncAttributeMaxDynamicSharedMemorySize, SMEM_BYTES);
  gm_kernel<<<dim3(NB), dim3(512), SMEM_BYTES, stream>>>(K, V, OUT);
}